// Round 2
// baseline (291.021 us; speedup 1.0000x reference)
//
#include <hip/hip_runtime.h>
#include <hip/hip_bf16.h>

typedef __attribute__((ext_vector_type(4))) float f32x4;
typedef __attribute__((ext_vector_type(8))) short s16x8;
typedef unsigned short ushort_t;

// ---------- helpers ----------
__device__ __forceinline__ ushort_t f2bf(float f) {
    union { float f; unsigned u; } v; v.f = f;
    unsigned r = v.u + 0x7fffu + ((v.u >> 16) & 1u);   // RNE
    return (ushort_t)(r >> 16);
}

__device__ __forceinline__ void gload16(const ushort_t* g, ushort_t* l) {
    __builtin_amdgcn_global_load_lds(
        (const __attribute__((address_space(1))) unsigned int*)g,
        (__attribute__((address_space(3))) unsigned int*)l,
        16, 0, 0);
}

#define BAR()  asm volatile("s_barrier" ::: "memory")
#define LGK0() do { asm volatile("s_waitcnt lgkmcnt(0)" ::: "memory"); __builtin_amdgcn_sched_barrier(0); } while (0)
#define VMC(n) asm volatile("s_waitcnt vmcnt(" #n ")" ::: "memory")

// ---------- fp32 -> bf16 conversion (8 elems/thread) ----------
__global__ void cvt_bf16(const float* __restrict__ in, ushort_t* __restrict__ out, int n8) {
    int i = blockIdx.x * blockDim.x + threadIdx.x;
    if (i >= n8) return;
    const float4* p = (const float4*)in;
    float4 a = p[2 * i], b = p[2 * i + 1];
    s16x8 v;
    v[0] = (short)f2bf(a.x); v[1] = (short)f2bf(a.y);
    v[2] = (short)f2bf(a.z); v[3] = (short)f2bf(a.w);
    v[4] = (short)f2bf(b.x); v[5] = (short)f2bf(b.y);
    v[6] = (short)f2bf(b.z); v[7] = (short)f2bf(b.w);
    *(s16x8*)(out + (size_t)i * 8) = v;
}

// ---------- RoPE tables ----------
__global__ void rope_tab_k(float* __restrict__ cosT, float* __restrict__ sinT) {
    int i = blockIdx.x * blockDim.x + threadIdx.x;   // 8192 total
    int l = i >> 5, fi = i & 31;
    float inv = powf(10000.f, -2.f * (float)fi / 64.f);
    float ang = (float)l * inv;
    cosT[i] = cosf(ang);
    sinT[i] = sinf(ang);
}

// ---------- 256x256 8-phase GEMM: C = A(Mx1024) * W(Nx1024)^T ----------
// BM=BN=256, BK=64, 8 waves (2Mx4N), LDS 128KiB double-buffered,
// XOR slot-swizzle (read-side + pre-swizzled global source), counted vmcnt(6).

// stage one 128x64 half-tile: linear LDS dest, inverse-swizzled global source.
__device__ __forceinline__ void stage_half(const ushort_t* __restrict__ src,
                                           ushort_t* chunk, int tid) {
#pragma unroll
    for (int j = 0; j < 2; ++j) {
        int row = (tid >> 3) + j * 64;
        int gslot = (tid & 7) ^ (row & 7);
        gload16(src + (size_t)row * 1024 + gslot * 8,
                chunk + (size_t)tid * 8 + (size_t)j * 4096);
    }
}

__device__ __forceinline__ s16x8 rdA(const ushort_t* chunk, int m, int kh, int lane) {
    int row = m * 16 + (lane & 15);
    int slot = (kh * 4 + (lane >> 4)) ^ (row & 7);
    return *(const s16x8*)&chunk[row * 64 + (slot << 3)];
}
__device__ __forceinline__ s16x8 rdB(const ushort_t* chunk, int wn, int n, int kh, int lane) {
    int row = (wn & 1) * 64 + n * 16 + (lane & 15);
    int slot = (kh * 4 + (lane >> 4)) ^ (row & 7);
    return *(const s16x8*)&chunk[row * 64 + (slot << 3)];
}

#define MFMA_Q(q, x, y)                                                                              \
    do {                                                                                             \
        _Pragma("unroll") for (int n_ = 0; n_ < 4; ++n_) {                                           \
            acc[2*(q)][n_]   = __builtin_amdgcn_mfma_f32_16x16x32_bf16(x[0], b_[n_][0], acc[2*(q)][n_], 0, 0, 0);   \
            acc[2*(q)][n_]   = __builtin_amdgcn_mfma_f32_16x16x32_bf16(x[1], b_[n_][1], acc[2*(q)][n_], 0, 0, 0);   \
            acc[2*(q)+1][n_] = __builtin_amdgcn_mfma_f32_16x16x32_bf16(y[0], b_[n_][0], acc[2*(q)+1][n_], 0, 0, 0); \
            acc[2*(q)+1][n_] = __builtin_amdgcn_mfma_f32_16x16x32_bf16(y[1], b_[n_][1], acc[2*(q)+1][n_], 0, 0, 0); \
        }                                                                                            \
    } while (0)

// MODE 0: fused QKV (N=3072 -> q/k/v bf16 + bias + rope on q,k)
// MODE 1: out-proj (N=1024 -> fp32 + bias)
template <int MODE>
__global__ __launch_bounds__(512, 2) void gemm256(const ushort_t* __restrict__ A,
                                                  const ushort_t* __restrict__ Wt,
                                                  const float* __restrict__ bz0,
                                                  const float* __restrict__ bz1,
                                                  const float* __restrict__ bz2,
                                                  ushort_t* __restrict__ o0,
                                                  ushort_t* __restrict__ o1,
                                                  ushort_t* __restrict__ o2,
                                                  float* __restrict__ of,
                                                  const float* __restrict__ cosT,
                                                  const float* __restrict__ sinT,
                                                  int ntn) {
    __shared__ ushort_t lds[2][4][8192];   // [buf][0=A0,1=A1,2=B0,3=B1][128*64]
#define Lc(b, c) (&lds[b][c][0])

    const int nwg = 64 * ntn;
    const int orig = blockIdx.x;
    const int wg = (orig % 8) * (nwg / 8) + orig / 8;   // bijective XCD swizzle (nwg%8==0)
    const int tm = wg % 64, tn = wg / 64;

    const int tid = threadIdx.x, lane = tid & 63, wid = tid >> 6;
    const int wm = wid >> 2, wn = wid & 3;

    f32x4 acc[8][4];
#pragma unroll
    for (int i = 0; i < 8; ++i)
#pragma unroll
        for (int j = 0; j < 4; ++j) acc[i][j] = (f32x4){0.f, 0.f, 0.f, 0.f};

    const ushort_t* Abase = A + (size_t)(tm * 256) * 1024;
    const ushort_t* Bbase = Wt + (size_t)(tn * 256) * 1024;

    // ---- prologue: tile0 (B0,B1,A0,A1) ; drain ; tile1 (B0,B1,A0) ----
    stage_half(Bbase, Lc(0, 2), tid);
    stage_half(Bbase + (size_t)128 * 1024, Lc(0, 3), tid);
    stage_half(Abase, Lc(0, 0), tid);
    stage_half(Abase + (size_t)128 * 1024, Lc(0, 1), tid);
    VMC(0);
    BAR();
    stage_half(Bbase + 64, Lc(1, 2), tid);
    stage_half(Bbase + (size_t)128 * 1024 + 64, Lc(1, 3), tid);
    stage_half(Abase + 64, Lc(1, 0), tid);

    // ---- main loop: 16 K-tiles, 4 phases each ----
#pragma unroll 1
    for (int u = 0; u < 16; ++u) {
        const int bu = u & 1;
        const ushort_t* cA = Lc(bu, wm);
        const ushort_t* cB = Lc(bu, 2 + (wn >> 1));
        const int kk1 = (u + 1 < 16 ? u + 1 : 15) * 64;
        const int kk2 = (u + 2 < 16 ? u + 2 : 15) * 64;
        s16x8 b_[4][2], a0[2], a1[2], a2[2], a3[2], a4[2], a5[2], a6[2], a7[2];

        // ---- phase A: B(8) + A m0,m1(4) reads; stage (u+1).A1; MFMA q0 ----
        VMC(6);
#pragma unroll
        for (int n = 0; n < 4; ++n)
#pragma unroll
            for (int kh = 0; kh < 2; ++kh) b_[n][kh] = rdB(cB, wn, n, kh, lane);
#pragma unroll
        for (int kh = 0; kh < 2; ++kh) { a0[kh] = rdA(cA, 0, kh, lane); a1[kh] = rdA(cA, 1, kh, lane); }
        stage_half(Abase + (size_t)128 * 1024 + kk1, Lc((u + 1) & 1, 1), tid);
        BAR(); LGK0();
        __builtin_amdgcn_s_setprio(1);
        MFMA_Q(0, a0, a1);
        __builtin_amdgcn_s_setprio(0);
        BAR();

        // ---- phase B: A m2..m5 reads; stage (u+2).B0; MFMA q1 ----
#pragma unroll
        for (int kh = 0; kh < 2; ++kh) {
            a2[kh] = rdA(cA, 2, kh, lane); a3[kh] = rdA(cA, 3, kh, lane);
            a4[kh] = rdA(cA, 4, kh, lane); a5[kh] = rdA(cA, 5, kh, lane);
        }
        stage_half(Bbase + kk2, Lc(bu, 2), tid);
        BAR(); LGK0();
        __builtin_amdgcn_s_setprio(1);
        MFMA_Q(1, a2, a3);
        __builtin_amdgcn_s_setprio(0);
        BAR();

        // ---- phase C: A m6,m7 reads; stage (u+2).B1; MFMA q2 ----
#pragma unroll
        for (int kh = 0; kh < 2; ++kh) { a6[kh] = rdA(cA, 6, kh, lane); a7[kh] = rdA(cA, 7, kh, lane); }
        stage_half(Bbase + (size_t)128 * 1024 + kk2, Lc(bu, 3), tid);
        BAR(); LGK0();
        __builtin_amdgcn_s_setprio(1);
        MFMA_Q(2, a4, a5);
        __builtin_amdgcn_s_setprio(0);
        BAR();

        // ---- phase D: stage (u+2).A0; MFMA q3 ----
        stage_half(Abase + kk2, Lc(bu, 0), tid);
        BAR(); LGK0();
        __builtin_amdgcn_s_setprio(1);
        MFMA_Q(3, a6, a7);
        __builtin_amdgcn_s_setprio(0);
        BAR();
    }
    VMC(0);

    // ---- epilogue ----
    const int rb0 = tm * 256 + wm * 128 + ((lane >> 4) << 2);
    if (MODE == 0) {
        const int zz = (tn * 256) >> 10;                         // uniform per block
        const float* bias = (zz == 0) ? bz0 : (zz == 1) ? bz1 : bz2;
        ushort_t* outp = (zz == 0) ? o0 : (zz == 1) ? o1 : o2;
        const bool rope = (zz < 2);
        const int cb = (tn & 3) * 256 + wn * 64;
#pragma unroll
        for (int m = 0; m < 8; ++m) {
#pragma unroll
            for (int n = 0; n < 4; ++n) {
                int col = cb + n * 16 + (lane & 15);
                float bv_ = bias[col];
                int rb = rb0 + m * 16;
#pragma unroll
                for (int r = 0; r < 4; ++r) {
                    float v = acc[m][n][r] + bv_;
                    float res;
                    if (rope) {
                        int l = (rb + r) & 255;
                        int fi = (col & 63) >> 1;
                        float c = cosT[l * 32 + fi], s = sinT[l * 32 + fi];
                        float partner = __shfl_xor(v, 1);
                        res = (col & 1) ? (v * c + partner * s) : (v * c - partner * s);
                    } else {
                        res = v;
                    }
                    outp[(size_t)(rb + r) * 1024 + col] = f2bf(res);
                }
            }
        }
    } else {
        const int cb = wn * 64;   // ntn=4 -> tn*256 spans 0..1023
        const int cfull = tn * 256 + cb;
#pragma unroll
        for (int m = 0; m < 8; ++m) {
#pragma unroll
            for (int n = 0; n < 4; ++n) {
                int col = cfull + n * 16 + (lane & 15);
                float bv_ = bz0[col];
                int rb = rb0 + m * 16;
#pragma unroll
                for (int r = 0; r < 4; ++r)
                    of[(size_t)(rb + r) * 1024 + col] = acc[m][n][r] + bv_;
            }
        }
    }
#undef Lc
}

// ---------- fused causal attention per (b,h) ----------
__global__ __launch_bounds__(512) void attn_kernel(const ushort_t* __restrict__ qb,
                                                   const ushort_t* __restrict__ kb,
                                                   const ushort_t* __restrict__ vb,
                                                   ushort_t* __restrict__ ab) {
    __shared__ ushort_t Ks[256 * 72];
    __shared__ ushort_t Vt[64 * 264];
    __shared__ ushort_t Ps[8][16 * 264];
    const int bh = blockIdx.x, b = bh >> 4, h = bh & 15;
    const int tid = threadIdx.x, lane = tid & 63, wid = tid >> 6;
    const size_t base = (size_t)b * 256 * 1024 + (size_t)h * 64;

#pragma unroll
    for (int it = 0; it < 4; ++it) {
        int c = tid + it * 512;
        int row = c >> 3, seg = c & 7;
        *(s16x8*)&Ks[row * 72 + seg * 8] =
            *(const s16x8*)&kb[base + (size_t)row * 1024 + seg * 8];
    }
#pragma unroll
    for (int it = 0; it < 4; ++it) {
        int c = tid + it * 512;
        int k = c >> 3, seg = c & 7;
        s16x8 v8 = *(const s16x8*)&vb[base + (size_t)k * 1024 + seg * 8];
#pragma unroll
        for (int j = 0; j < 8; ++j)
            Vt[(seg * 8 + j) * 264 + k] = (ushort_t)v8[j];
    }
    __syncthreads();

#pragma unroll
    for (int ch = 0; ch < 2; ++ch) {
        const int q0 = wid * 32 + ch * 16;
        const int ntop = q0 >> 4;    // last contributing 16-col tile
        s16x8 aq0 = *(const s16x8*)&qb[base + (size_t)(q0 + (lane & 15)) * 1024 + ((lane >> 4) << 3)];
        s16x8 aq1 = *(const s16x8*)&qb[base + (size_t)(q0 + (lane & 15)) * 1024 + 32 + ((lane >> 4) << 3)];

        f32x4 sacc[16];
#pragma unroll
        for (int n = 0; n < 16; ++n) sacc[n] = (f32x4){0.f, 0.f, 0.f, 0.f};
#pragma unroll
        for (int n = 0; n < 16; ++n) {
            if (n <= ntop) {
                const int kr = (n * 16 + (lane & 15)) * 72 + ((lane >> 4) << 3);
                s16x8 b0 = *(const s16x8*)&Ks[kr];
                s16x8 b1 = *(const s16x8*)&Ks[kr + 32];
                sacc[n] = __builtin_amdgcn_mfma_f32_16x16x32_bf16(aq0, b0, sacc[n], 0, 0, 0);
                sacc[n] = __builtin_amdgcn_mfma_f32_16x16x32_bf16(aq1, b1, sacc[n], 0, 0, 0);
            }
        }

        float rinv[4];
#pragma unroll
        for (int r = 0; r < 4; ++r) {
            const int row = q0 + ((lane >> 4) << 2) + r;
            float m = -1e30f;
#pragma unroll
            for (int n = 0; n < 16; ++n) {
                int col = n * 16 + (lane & 15);
                float v = (col <= row) ? sacc[n][r] * 0.125f : -1e30f;
                sacc[n][r] = v;
                m = fmaxf(m, v);
            }
            m = fmaxf(m, __shfl_xor(m, 1));
            m = fmaxf(m, __shfl_xor(m, 2));
            m = fmaxf(m, __shfl_xor(m, 4));
            m = fmaxf(m, __shfl_xor(m, 8));
            float sum = 0.f;
#pragma unroll
            for (int n = 0; n < 16; ++n) {
                float p = __expf(sacc[n][r] - m);
                sacc[n][r] = p;
                sum += p;
            }
            sum += __shfl_xor(sum, 1);
            sum += __shfl_xor(sum, 2);
            sum += __shfl_xor(sum, 4);
            sum += __shfl_xor(sum, 8);
            rinv[r] = 1.f / sum;
#pragma unroll
            for (int n = 0; n < 16; ++n)
                Ps[wid][(((lane >> 4) << 2) + r) * 264 + n * 16 + (lane & 15)] = f2bf(sacc[n][r]);
        }
        __syncthreads();

        f32x4 oa[4];
#pragma unroll
        for (int dt = 0; dt < 4; ++dt) oa[dt] = (f32x4){0.f, 0.f, 0.f, 0.f};
        const int kstop = q0 >> 5;
#pragma unroll
        for (int ks = 0; ks < 8; ++ks) {
            if (ks <= kstop) {
                s16x8 pf = *(const s16x8*)&Ps[wid][(lane & 15) * 264 + ks * 32 + ((lane >> 4) << 3)];
#pragma unroll
                for (int dt = 0; dt < 4; ++dt) {
                    s16x8 vf = *(const s16x8*)&Vt[(dt * 16 + (lane & 15)) * 264 + ks * 32 + ((lane >> 4) << 3)];
                    oa[dt] = __builtin_amdgcn_mfma_f32_16x16x32_bf16(pf, vf, oa[dt], 0, 0, 0);
                }
            }
        }
#pragma unroll
        for (int dt = 0; dt < 4; ++dt) {
#pragma unroll
            for (int r = 0; r < 4; ++r) {
                int row = q0 + ((lane >> 4) << 2) + r;
                int col = h * 64 + dt * 16 + (lane & 15);
                ab[(size_t)(b * 256 + row) * 1024 + col] = f2bf(oa[dt][r] * rinv[r]);
            }
        }
        __syncthreads();
    }
}

// ---------- launch ----------
extern "C" void kernel_launch(void* const* d_in, const int* in_sizes, int n_in,
                              void* d_out, int out_size, void* d_ws, size_t ws_size,
                              hipStream_t stream) {
    (void)in_sizes; (void)n_in; (void)out_size;
    const float* x  = (const float*)d_in[0];
    const float* Wq = (const float*)d_in[1];
    const float* bq = (const float*)d_in[2];
    const float* Wk = (const float*)d_in[3];
    const float* bk = (const float*)d_in[4];
    const float* Wv = (const float*)d_in[5];
    const float* bv = (const float*)d_in[6];
    const float* Wo = (const float*)d_in[7];
    const float* bo = (const float*)d_in[8];
    float* out = (float*)d_out;

    const size_t M = 16384, E = 1024;
    char* ws = (char*)d_ws;
    ushort_t* xb   = (ushort_t*)ws;          // M*E (aliased as attn out later)
    ushort_t* wqkv = xb + M * E;             // 3*E*E, concat [Wq;Wk;Wv]
    ushort_t* wob  = wqkv + 3 * E * E;
    ushort_t* qb   = wob + E * E;
    ushort_t* kb   = qb + M * E;
    ushort_t* vb   = kb + M * E;
    float* cosT    = (float*)(vb + M * E);
    float* sinT    = cosT + 256 * 32;
    ushort_t* ab   = xb;

    size_t need = (4 * M * E + 4 * E * E) * sizeof(ushort_t) + 2 * 256 * 32 * sizeof(float);
    if (ws_size < need) return;

    cvt_bf16<<<8192, 256, 0, stream>>>(x, xb, (int)(M * E / 8));
    cvt_bf16<<<512, 256, 0, stream>>>(Wq, wqkv, (int)(E * E / 8));
    cvt_bf16<<<512, 256, 0, stream>>>(Wk, wqkv + E * E, (int)(E * E / 8));
    cvt_bf16<<<512, 256, 0, stream>>>(Wv, wqkv + 2 * E * E, (int)(E * E / 8));
    cvt_bf16<<<512, 256, 0, stream>>>(Wo, wob, (int)(E * E / 8));
    rope_tab_k<<<32, 256, 0, stream>>>(cosT, sinT);

    gemm256<0><<<768, 512, 0, stream>>>(xb, wqkv, bq, bk, bv, qb, kb, vb, nullptr,
                                        cosT, sinT, 12);
    attn_kernel<<<1024, 512, 0, stream>>>(qb, kb, vb, ab);
    gemm256<1><<<256, 512, 0, stream>>>(ab, wob, bo, nullptr, nullptr,
                                        nullptr, nullptr, nullptr, out, nullptr, nullptr, 4);
}

// Round 3
// 282.807 us; speedup vs baseline: 1.0290x; 1.0290x over previous
//
#include <hip/hip_runtime.h>
#include <hip/hip_bf16.h>

typedef __attribute__((ext_vector_type(4))) float f32x4;
typedef __attribute__((ext_vector_type(8))) short s16x8;
typedef unsigned short ushort_t;

// ---------- helpers ----------
__device__ __forceinline__ ushort_t f2bf(float f) {
    union { float f; unsigned u; } v; v.f = f;
    unsigned r = v.u + 0x7fffu + ((v.u >> 16) & 1u);   // RNE
    return (ushort_t)(r >> 16);
}

__device__ __forceinline__ void gload16(const ushort_t* g, ushort_t* l) {
    __builtin_amdgcn_global_load_lds(
        (const __attribute__((address_space(1))) unsigned int*)g,
        (__attribute__((address_space(3))) unsigned int*)l,
        16, 0, 0);
}

#define BAR()  asm volatile("s_barrier" ::: "memory")
#define LGK0() do { asm volatile("s_waitcnt lgkmcnt(0)" ::: "memory"); __builtin_amdgcn_sched_barrier(0); } while (0)
#define VMC(n) asm volatile("s_waitcnt vmcnt(" #n ")" ::: "memory")

// ---------- fp32 -> bf16 conversion (8 elems/thread) ----------
__global__ void cvt_bf16(const float* __restrict__ in, ushort_t* __restrict__ out, int n8) {
    int i = blockIdx.x * blockDim.x + threadIdx.x;
    if (i >= n8) return;
    const float4* p = (const float4*)in;
    float4 a = p[2 * i], b = p[2 * i + 1];
    s16x8 v;
    v[0] = (short)f2bf(a.x); v[1] = (short)f2bf(a.y);
    v[2] = (short)f2bf(a.z); v[3] = (short)f2bf(a.w);
    v[4] = (short)f2bf(b.x); v[5] = (short)f2bf(b.y);
    v[6] = (short)f2bf(b.z); v[7] = (short)f2bf(b.w);
    *(s16x8*)(out + (size_t)i * 8) = v;
}

// ---------- RoPE tables ----------
__global__ void rope_tab_k(float* __restrict__ cosT, float* __restrict__ sinT) {
    int i = blockIdx.x * blockDim.x + threadIdx.x;   // 8192 total
    int l = i >> 5, fi = i & 31;
    float inv = powf(10000.f, -2.f * (float)fi / 64.f);
    float ang = (float)l * inv;
    cosT[i] = cosf(ang);
    sinT[i] = sinf(ang);
}

// ---------- 256x256 8-phase GEMM: C = A(Mx1024) * W(Nx1024)^T ----------
// BM=BN=256, BK=64, 8 waves (2Mx4N), LDS 128KiB double-buffered,
// XOR slot-swizzle (read-side + pre-swizzled global source), counted vmcnt(6).
// Block mapping: XCD-bijective chunks, tn fastest within chunk (A-panel L2 reuse).

__device__ __forceinline__ void stage_half(const ushort_t* __restrict__ src,
                                           ushort_t* chunk, int tid) {
#pragma unroll
    for (int j = 0; j < 2; ++j) {
        int row = (tid >> 3) + j * 64;
        int gslot = (tid & 7) ^ (row & 7);
        gload16(src + (size_t)row * 1024 + gslot * 8,
                chunk + (size_t)tid * 8 + (size_t)j * 4096);
    }
}

__device__ __forceinline__ s16x8 rdA(const ushort_t* chunk, int m, int kh, int lane) {
    int row = m * 16 + (lane & 15);
    int slot = (kh * 4 + (lane >> 4)) ^ (row & 7);
    return *(const s16x8*)&chunk[row * 64 + (slot << 3)];
}
__device__ __forceinline__ s16x8 rdB(const ushort_t* chunk, int wn, int n, int kh, int lane) {
    int row = (wn & 1) * 64 + n * 16 + (lane & 15);
    int slot = (kh * 4 + (lane >> 4)) ^ (row & 7);
    return *(const s16x8*)&chunk[row * 64 + (slot << 3)];
}

#define MFMA_Q(q, x, y)                                                                              \
    do {                                                                                             \
        _Pragma("unroll") for (int n_ = 0; n_ < 4; ++n_) {                                           \
            acc[2*(q)][n_]   = __builtin_amdgcn_mfma_f32_16x16x32_bf16(x[0], b_[n_][0], acc[2*(q)][n_], 0, 0, 0);   \
            acc[2*(q)][n_]   = __builtin_amdgcn_mfma_f32_16x16x32_bf16(x[1], b_[n_][1], acc[2*(q)][n_], 0, 0, 0);   \
            acc[2*(q)+1][n_] = __builtin_amdgcn_mfma_f32_16x16x32_bf16(y[0], b_[n_][0], acc[2*(q)+1][n_], 0, 0, 0); \
            acc[2*(q)+1][n_] = __builtin_amdgcn_mfma_f32_16x16x32_bf16(y[1], b_[n_][1], acc[2*(q)+1][n_], 0, 0, 0); \
        }                                                                                            \
    } while (0)

// MODE 0: fused QKV (N=3072 -> q/k/v bf16 + bias + rope on q,k)
// MODE 1: out-proj (N=1024 -> fp32 + bias)
template <int MODE>
__global__ __launch_bounds__(512, 2) void gemm256(const ushort_t* __restrict__ A,
                                                  const ushort_t* __restrict__ Wt,
                                                  const float* __restrict__ bz0,
                                                  const float* __restrict__ bz1,
                                                  const float* __restrict__ bz2,
                                                  ushort_t* __restrict__ o0,
                                                  ushort_t* __restrict__ o1,
                                                  ushort_t* __restrict__ o2,
                                                  float* __restrict__ of,
                                                  const float* __restrict__ cosT,
                                                  const float* __restrict__ sinT,
                                                  int ntn) {
    __shared__ ushort_t lds[2][4][8192];   // [buf][0=A0,1=A1,2=B0,3=B1][128*64]
#define Lc(b, c) (&lds[b][c][0])

    const int nwg = 64 * ntn;
    const int orig = blockIdx.x;
    const int wg = (orig % 8) * (nwg / 8) + orig / 8;   // bijective XCD swizzle (nwg%8==0)
    const int tn = wg % ntn, tm = wg / ntn;             // tn fastest: A-panel stays L2-hot

    const int tid = threadIdx.x, lane = tid & 63, wid = tid >> 6;
    const int wm = wid >> 2, wn = wid & 3;

    f32x4 acc[8][4];
#pragma unroll
    for (int i = 0; i < 8; ++i)
#pragma unroll
        for (int j = 0; j < 4; ++j) acc[i][j] = (f32x4){0.f, 0.f, 0.f, 0.f};

    const ushort_t* Abase = A + (size_t)(tm * 256) * 1024;
    const ushort_t* Bbase = Wt + (size_t)(tn * 256) * 1024;

    // ---- prologue: tile0 (B0,B1,A0,A1) ; drain ; tile1 (B0,B1,A0) ----
    stage_half(Bbase, Lc(0, 2), tid);
    stage_half(Bbase + (size_t)128 * 1024, Lc(0, 3), tid);
    stage_half(Abase, Lc(0, 0), tid);
    stage_half(Abase + (size_t)128 * 1024, Lc(0, 1), tid);
    VMC(0);
    BAR();
    stage_half(Bbase + 64, Lc(1, 2), tid);
    stage_half(Bbase + (size_t)128 * 1024 + 64, Lc(1, 3), tid);
    stage_half(Abase + 64, Lc(1, 0), tid);

    // ---- main loop: 16 K-tiles, 4 phases each ----
#pragma unroll 1
    for (int u = 0; u < 16; ++u) {
        const int bu = u & 1;
        const ushort_t* cA = Lc(bu, wm);
        const ushort_t* cB = Lc(bu, 2 + (wn >> 1));
        const int kk1 = (u + 1 < 16 ? u + 1 : 15) * 64;
        const int kk2 = (u + 2 < 16 ? u + 2 : 15) * 64;
        s16x8 b_[4][2], a0[2], a1[2], a2[2], a3[2], a4[2], a5[2], a6[2], a7[2];

        // ---- phase A: B(8) + A m0,m1(4) reads; stage (u+1).A1; MFMA q0 ----
        VMC(6);
#pragma unroll
        for (int n = 0; n < 4; ++n)
#pragma unroll
            for (int kh = 0; kh < 2; ++kh) b_[n][kh] = rdB(cB, wn, n, kh, lane);
#pragma unroll
        for (int kh = 0; kh < 2; ++kh) { a0[kh] = rdA(cA, 0, kh, lane); a1[kh] = rdA(cA, 1, kh, lane); }
        stage_half(Abase + (size_t)128 * 1024 + kk1, Lc((u + 1) & 1, 1), tid);
        BAR(); LGK0();
        __builtin_amdgcn_s_setprio(1);
        MFMA_Q(0, a0, a1);
        __builtin_amdgcn_s_setprio(0);
        BAR();

        // ---- phase B: A m2..m5 reads; stage (u+2).B0; MFMA q1 ----
#pragma unroll
        for (int kh = 0; kh < 2; ++kh) {
            a2[kh] = rdA(cA, 2, kh, lane); a3[kh] = rdA(cA, 3, kh, lane);
            a4[kh] = rdA(cA, 4, kh, lane); a5[kh] = rdA(cA, 5, kh, lane);
        }
        stage_half(Bbase + kk2, Lc(bu, 2), tid);
        BAR(); LGK0();
        __builtin_amdgcn_s_setprio(1);
        MFMA_Q(1, a2, a3);
        __builtin_amdgcn_s_setprio(0);
        BAR();

        // ---- phase C: A m6,m7 reads; stage (u+2).B1; MFMA q2 ----
#pragma unroll
        for (int kh = 0; kh < 2; ++kh) { a6[kh] = rdA(cA, 6, kh, lane); a7[kh] = rdA(cA, 7, kh, lane); }
        stage_half(Bbase + (size_t)128 * 1024 + kk2, Lc(bu, 3), tid);
        BAR(); LGK0();
        __builtin_amdgcn_s_setprio(1);
        MFMA_Q(2, a4, a5);
        __builtin_amdgcn_s_setprio(0);
        BAR();

        // ---- phase D: stage (u+2).A0; MFMA q3 ----
        stage_half(Abase + kk2, Lc(bu, 0), tid);
        BAR(); LGK0();
        __builtin_amdgcn_s_setprio(1);
        MFMA_Q(3, a6, a7);
        __builtin_amdgcn_s_setprio(0);
        BAR();
    }
    VMC(0);

    // ---- epilogue ----
    const int rb0 = tm * 256 + wm * 128 + ((lane >> 4) << 2);
    if (MODE == 0) {
        const int zz = (tn * 256) >> 10;                         // uniform per block
        const float* bias = (zz == 0) ? bz0 : (zz == 1) ? bz1 : bz2;
        ushort_t* outp = (zz == 0) ? o0 : (zz == 1) ? o1 : o2;
        const bool rope = (zz < 2);
        const int cb = (tn & 3) * 256 + wn * 64;
#pragma unroll
        for (int m = 0; m < 8; ++m) {
#pragma unroll
            for (int n = 0; n < 4; ++n) {
                int col = cb + n * 16 + (lane & 15);
                float bv_ = bias[col];
                int rb = rb0 + m * 16;
#pragma unroll
                for (int r = 0; r < 4; ++r) {
                    float v = acc[m][n][r] + bv_;
                    float res;
                    if (rope) {
                        int l = (rb + r) & 255;
                        int fi = (col & 63) >> 1;
                        float c = cosT[l * 32 + fi], s = sinT[l * 32 + fi];
                        float partner = __shfl_xor(v, 1);
                        res = (col & 1) ? (v * c + partner * s) : (v * c - partner * s);
                    } else {
                        res = v;
                    }
                    outp[(size_t)(rb + r) * 1024 + col] = f2bf(res);
                }
            }
        }
    } else {
        const int cb = wn * 64;
        const int cfull = tn * 256 + cb;
#pragma unroll
        for (int m = 0; m < 8; ++m) {
#pragma unroll
            for (int n = 0; n < 4; ++n) {
                int col = cfull + n * 16 + (lane & 15);
                float bv_ = bz0[col];
                int rb = rb0 + m * 16;
#pragma unroll
                for (int r = 0; r < 4; ++r)
                    of[(size_t)(rb + r) * 1024 + col] = acc[m][n][r] + bv_;
            }
        }
    }
#undef Lc
}

// ---------- fused causal attention per (b,h) ----------
__global__ __launch_bounds__(512) void attn_kernel(const ushort_t* __restrict__ qb,
                                                   const ushort_t* __restrict__ kb,
                                                   const ushort_t* __restrict__ vb,
                                                   ushort_t* __restrict__ ab) {
    __shared__ ushort_t Ks[256 * 72];
    __shared__ ushort_t Vt[64 * 264];
    __shared__ ushort_t Ps[8][16 * 264];
    const int bh = blockIdx.x, b = bh >> 4, h = bh & 15;
    const int tid = threadIdx.x, lane = tid & 63, wid = tid >> 6;
    const size_t base = (size_t)b * 256 * 1024 + (size_t)h * 64;

#pragma unroll
    for (int it = 0; it < 4; ++it) {
        int c = tid + it * 512;
        int row = c >> 3, seg = c & 7;
        *(s16x8*)&Ks[row * 72 + seg * 8] =
            *(const s16x8*)&kb[base + (size_t)row * 1024 + seg * 8];
    }
#pragma unroll
    for (int it = 0; it < 4; ++it) {
        int c = tid + it * 512;
        int k = c >> 3, seg = c & 7;
        s16x8 v8 = *(const s16x8*)&vb[base + (size_t)k * 1024 + seg * 8];
#pragma unroll
        for (int j = 0; j < 8; ++j)
            Vt[(seg * 8 + j) * 264 + k] = (ushort_t)v8[j];
    }
    __syncthreads();

#pragma unroll
    for (int ch = 0; ch < 2; ++ch) {
        const int q0 = wid * 32 + ch * 16;
        const int ntop = q0 >> 4;
        s16x8 aq0 = *(const s16x8*)&qb[base + (size_t)(q0 + (lane & 15)) * 1024 + ((lane >> 4) << 3)];
        s16x8 aq1 = *(const s16x8*)&qb[base + (size_t)(q0 + (lane & 15)) * 1024 + 32 + ((lane >> 4) << 3)];

        f32x4 sacc[16];
#pragma unroll
        for (int n = 0; n < 16; ++n) sacc[n] = (f32x4){0.f, 0.f, 0.f, 0.f};
#pragma unroll
        for (int n = 0; n < 16; ++n) {
            if (n <= ntop) {
                const int kr = (n * 16 + (lane & 15)) * 72 + ((lane >> 4) << 3);
                s16x8 b0 = *(const s16x8*)&Ks[kr];
                s16x8 b1 = *(const s16x8*)&Ks[kr + 32];
                sacc[n] = __builtin_amdgcn_mfma_f32_16x16x32_bf16(aq0, b0, sacc[n], 0, 0, 0);
                sacc[n] = __builtin_amdgcn_mfma_f32_16x16x32_bf16(aq1, b1, sacc[n], 0, 0, 0);
            }
        }

        float rinv[4];
#pragma unroll
        for (int r = 0; r < 4; ++r) {
            const int row = q0 + ((lane >> 4) << 2) + r;
            float m = -1e30f;
#pragma unroll
            for (int n = 0; n < 16; ++n) {
                int col = n * 16 + (lane & 15);
                float v = (col <= row) ? sacc[n][r] * 0.125f : -1e30f;
                sacc[n][r] = v;
                m = fmaxf(m, v);
            }
            m = fmaxf(m, __shfl_xor(m, 1));
            m = fmaxf(m, __shfl_xor(m, 2));
            m = fmaxf(m, __shfl_xor(m, 4));
            m = fmaxf(m, __shfl_xor(m, 8));
            float sum = 0.f;
#pragma unroll
            for (int n = 0; n < 16; ++n) {
                float p = __expf(sacc[n][r] - m);
                sacc[n][r] = p;
                sum += p;
            }
            sum += __shfl_xor(sum, 1);
            sum += __shfl_xor(sum, 2);
            sum += __shfl_xor(sum, 4);
            sum += __shfl_xor(sum, 8);
            rinv[r] = 1.f / sum;
#pragma unroll
            for (int n = 0; n < 16; ++n)
                Ps[wid][(((lane >> 4) << 2) + r) * 264 + n * 16 + (lane & 15)] = f2bf(sacc[n][r]);
        }
        __syncthreads();

        f32x4 oa[4];
#pragma unroll
        for (int dt = 0; dt < 4; ++dt) oa[dt] = (f32x4){0.f, 0.f, 0.f, 0.f};
        const int kstop = q0 >> 5;
#pragma unroll
        for (int ks = 0; ks < 8; ++ks) {
            if (ks <= kstop) {
                s16x8 pf = *(const s16x8*)&Ps[wid][(lane & 15) * 264 + ks * 32 + ((lane >> 4) << 3)];
#pragma unroll
                for (int dt = 0; dt < 4; ++dt) {
                    s16x8 vf = *(const s16x8*)&Vt[(dt * 16 + (lane & 15)) * 264 + ks * 32 + ((lane >> 4) << 3)];
                    oa[dt] = __builtin_amdgcn_mfma_f32_16x16x32_bf16(pf, vf, oa[dt], 0, 0, 0);
                }
            }
        }
#pragma unroll
        for (int dt = 0; dt < 4; ++dt) {
#pragma unroll
            for (int r = 0; r < 4; ++r) {
                int row = q0 + ((lane >> 4) << 2) + r;
                int col = h * 64 + dt * 16 + (lane & 15);
                ab[(size_t)(b * 256 + row) * 1024 + col] = f2bf(oa[dt][r] * rinv[r]);
            }
        }
        __syncthreads();
    }
}

// ---------- launch ----------
extern "C" void kernel_launch(void* const* d_in, const int* in_sizes, int n_in,
                              void* d_out, int out_size, void* d_ws, size_t ws_size,
                              hipStream_t stream) {
    (void)in_sizes; (void)n_in; (void)out_size;
    const float* x  = (const float*)d_in[0];
    const float* Wq = (const float*)d_in[1];
    const float* bq = (const float*)d_in[2];
    const float* Wk = (const float*)d_in[3];
    const float* bk = (const float*)d_in[4];
    const float* Wv = (const float*)d_in[5];
    const float* bv = (const float*)d_in[6];
    const float* Wo = (const float*)d_in[7];
    const float* bo = (const float*)d_in[8];
    float* out = (float*)d_out;

    const size_t M = 16384, E = 1024;
    char* ws = (char*)d_ws;
    ushort_t* xb   = (ushort_t*)ws;          // M*E (aliased as attn out later)
    ushort_t* wqkv = xb + M * E;             // 3*E*E, concat [Wq;Wk;Wv]
    ushort_t* wob  = wqkv + 3 * E * E;
    ushort_t* qb   = wob + E * E;
    ushort_t* kb   = qb + M * E;
    ushort_t* vb   = kb + M * E;
    float* cosT    = (float*)(vb + M * E);
    float* sinT    = cosT + 256 * 32;
    ushort_t* ab   = xb;

    size_t need = (4 * M * E + 4 * E * E) * sizeof(ushort_t) + 2 * 256 * 32 * sizeof(float);
    if (ws_size < need) return;

    cvt_bf16<<<8192, 256, 0, stream>>>(x, xb, (int)(M * E / 8));
    cvt_bf16<<<512, 256, 0, stream>>>(Wq, wqkv, (int)(E * E / 8));
    cvt_bf16<<<512, 256, 0, stream>>>(Wk, wqkv + E * E, (int)(E * E / 8));
    cvt_bf16<<<512, 256, 0, stream>>>(Wv, wqkv + 2 * E * E, (int)(E * E / 8));
    cvt_bf16<<<512, 256, 0, stream>>>(Wo, wob, (int)(E * E / 8));
    rope_tab_k<<<32, 256, 0, stream>>>(cosT, sinT);

    gemm256<0><<<768, 512, 0, stream>>>(xb, wqkv, bq, bk, bv, qb, kb, vb, nullptr,
                                        cosT, sinT, 12);
    attn_kernel<<<1024, 512, 0, stream>>>(qb, kb, vb, ab);
    gemm256<1><<<256, 512, 0, stream>>>(ab, wob, bo, nullptr, nullptr,
                                        nullptr, nullptr, nullptr, out, nullptr, nullptr, 4);
}